// Round 5
// baseline (243.745 us; speedup 1.0000x reference)
//
#include <hip/hip_runtime.h>
#include <hip/hip_bf16.h>

typedef float f32x4 __attribute__((ext_vector_type(4)));
typedef int v8i __attribute__((ext_vector_type(8)));

#define NB 8
#define ND 512
#define NT 2048
#define NCODES 4096
#define NM (NB * NT)
#define MARGIN_F 0.2f
#define ENC_STRIDE 320

// MX fragment image (Zq, Cq), fp8 e4m3:
//   tile (R_, K_) = 128 rows x 128 k = 16 KB at ((R_*4 + K_) * 16384)
//   fragment rg (0..7) = 16 rows x 128 k = 2048 B at rg*2048 within tile
//   bytes [0,1024): lane l's 16 B at l*16 = row rg*16+(l&15), k = (l>>4)*32 + 0..15
//   bytes [1024,2048): same lanes, k = (l>>4)*32 + 16..31

// Map a linear rank to the rank-th SURVIVING tile (tiles of 2^shift rows within each
// batch's valid prefix). Survivor compaction keeps live blocks contiguous in blockIdx.
static __device__ inline bool rank_decode(const int* __restrict__ lengths, int rank,
                                          int shift, int& b, int& tib) {
    int acc = 0;
    bool ok = false;
#pragma unroll
    for (int bb = 0; bb < NB; bb++) {
        int fl = lengths[bb] / ENC_STRIDE;
        int c = (fl + ((1 << shift) - 1)) >> shift;  // ceil(fl / tile_rows)
        if (!ok && rank < acc + c) { b = bb; tib = rank - acc; ok = true; }
        acc += c;
    }
    return ok;
}

// ---- kernel 1: fused prep. blocks [0,1024): student (compacted); [1024,1280): codebook ----
__global__ void prep_fused(const float* __restrict__ sf, const float* __restrict__ cb,
                           const int* __restrict__ lengths,
                           unsigned char* __restrict__ Zq, float* __restrict__ npart,
                           unsigned char* __restrict__ Cq, float* __restrict__ cnorm,
                           float* __restrict__ accum, unsigned int* __restrict__ ticket) {
    __shared__ float tile[128][65];
    __shared__ float redc[4][16];
    const int tid = threadIdx.x;  // 256
    const int wave = tid >> 6, lane = tid & 63, l15 = lane & 15, kq = lane >> 4;

    if (blockIdx.x < 1024) {
        const int bx = blockIdx.x;
        int b, tt;
        if (!rank_decode(lengths, bx >> 2, 6, b, tt)) return;  // 64-row student tiles
        const int t0 = tt * 64;
        const int d0 = (bx & 3) * 128;
        const float* src = sf + (size_t)b * ND * NT;
#pragma unroll
        for (int it = 0; it < 8; it++) {
            int idx = it * 256 + tid;
            int d = idx >> 4, t4 = (idx & 15) * 4;
            float4 v = *(const float4*)(src + (size_t)(d0 + d) * NT + t0 + t4);  // coalesced
            tile[d][t4] = v.x; tile[d][t4 + 1] = v.y; tile[d][t4 + 2] = v.z; tile[d][t4 + 3] = v.w;
        }
        __syncthreads();
        const int m0 = b * NT + t0;
        {
            const int trow = wave * 16 + l15;
            unsigned char q[32];
#pragma unroll
            for (int j = 0; j < 32; j += 2) {
                float a = tile[kq * 32 + j][trow];
                float c = tile[kq * 32 + j + 1][trow];
                int p = __builtin_amdgcn_cvt_pk_fp8_f32(a, c, 0, false);
                q[j] = (unsigned char)(p & 0xFF);
                q[j + 1] = (unsigned char)((p >> 8) & 0xFF);
            }
            const int M_ = m0 >> 7, rg = ((m0 >> 4) & 7) + wave, K_ = d0 >> 7;
            char* base = (char*)Zq + ((size_t)((M_ * 4 + K_) * 8 + rg)) * 2048;
            *(uint4*)(base + lane * 16) = *(uint4*)&q[0];
            *(uint4*)(base + 1024 + lane * 16) = *(uint4*)&q[16];
        }
        if (tid < 64) {
            float s = 0.0f;
#pragma unroll 16
            for (int d = 0; d < 128; d++) {
                float v = tile[d][tid];
                s += v * v;
            }
            npart[(size_t)(d0 >> 7) * NM + m0 + tid] = s;
        }
    } else {
        if (blockIdx.x == 1279 && tid == 0) { *accum = 0.0f; *ticket = 0u; }
        const int r0 = (blockIdx.x - 1024) * 16;
        const int row = r0 + l15;
        const int K_ = wave;  // each wave handles one 128-k quarter
        const float* src = cb + (size_t)row * ND + K_ * 128 + kq * 32;
        unsigned char q[32];
        float s = 0.0f;
#pragma unroll
        for (int j4 = 0; j4 < 8; j4++) {
            float4 v = *(const float4*)(src + j4 * 4);
            s += v.x * v.x + v.y * v.y + v.z * v.z + v.w * v.w;
            int p0 = __builtin_amdgcn_cvt_pk_fp8_f32(v.x, v.y, 0, false);
            int p1 = __builtin_amdgcn_cvt_pk_fp8_f32(v.z, v.w, 0, false);
            q[j4 * 4 + 0] = (unsigned char)(p0 & 0xFF);
            q[j4 * 4 + 1] = (unsigned char)((p0 >> 8) & 0xFF);
            q[j4 * 4 + 2] = (unsigned char)(p1 & 0xFF);
            q[j4 * 4 + 3] = (unsigned char)((p1 >> 8) & 0xFF);
        }
        const int N_ = r0 >> 7, rg = (r0 >> 4) & 7;
        char* base = (char*)Cq + ((size_t)((N_ * 4 + K_) * 8 + rg)) * 2048;
        *(uint4*)(base + lane * 16) = *(uint4*)&q[0];
        *(uint4*)(base + 1024 + lane * 16) = *(uint4*)&q[16];
        s += __shfl_xor(s, 16);
        s += __shfl_xor(s, 32);
        if (lane < 16) redc[wave][l15] = s;
        __syncthreads();
        if (tid < 16) cnorm[r0 + tid] = redc[0][tid] + redc[1][tid] + redc[2][tid] + redc[3][tid];
    }
}

// ---- kernel 2: MX-fp8 GEMM, REGISTER-DIRECT (no LDS, no barriers) ----
// R0-R4 evidence: time invariant (52-53 us) under 2x work, 4x fetch, prefetch and
// compaction changes -> the LDS stage/barrier lockstep latency chain IS the cost,
// not any throughput pipe. Zq+Cq = 10 MB = L3-resident (Cq quarter L2-resident),
// and the fragment images are already in MFMA fragment order -> each wave loads its
// fragments straight to VGPRs (global_load_dwordx4, 1 KB/wave coalesced). No LDS ->
// no __syncthreads -> no vmcnt(0) drains; waves free-run with compiler-counted
// waitcnts. Trades block-level B reuse (~8x L2 read stream, ~15 us at measured L2
// BW) for removal of the 52 us latency floor. Guide Common-mistake #7.
__global__ __launch_bounds__(256, 2) void triplet_main(
    const unsigned char* __restrict__ Zq, const unsigned char* __restrict__ Cq,
    const float* __restrict__ cnorm, const int* __restrict__ teacher,
    const int* __restrict__ lengths,
    float* __restrict__ negq, float* __restrict__ posq) {
    int b, tM;
    if (!rank_decode(lengths, (int)blockIdx.x >> 3, 7, b, tM)) return;  // 128-row tiles
    const int nq = blockIdx.x & 7;
    const int M_ = b * 16 + tM;
    const int m0 = M_ * 128;

    const int tid = threadIdx.x;
    const int wave = tid >> 6, lane = tid & 63;
    const int wr = wave >> 1, wc = wave & 1;
    const int l15 = lane & 15, quad = lane >> 4;

    const float INF = __builtin_inff();
    float minv[4][4], posv[4][4];
    int tch[4][4];
#pragma unroll
    for (int mi = 0; mi < 4; mi++)
#pragma unroll
        for (int r = 0; r < 4; r++) {
            minv[mi][r] = INF;
            posv[mi][r] = INF;
            tch[mi][r] = teacher[m0 + wr * 64 + mi * 16 + quad * 4 + r];
        }

    // Per-wave fragment bases into the global fragment images.
    // A fragment mi of k-tile kt:  gA + kt*16384 + mi*2048 (+1024 for hi half)
    // B fragment ni of tile (nt,kt): gB + (nt*4+kt)*16384 + ni*2048 (+1024)
    const char* gA = (const char*)Zq + (size_t)(M_ * 4) * 16384 + (wr * 4) * 2048 + lane * 16;
    const char* gB = (const char*)Cq + (size_t)(nq * 16) * 16384 + (wc * 4) * 2048 + lane * 16;

#pragma unroll 1
    for (int nt = 0; nt < 4; ++nt) {
        f32x4 acc[4][4];
#pragma unroll
        for (int mi = 0; mi < 4; mi++)
#pragma unroll
            for (int ni = 0; ni < 4; ni++)
                acc[mi][ni] = (f32x4){0.f, 0.f, 0.f, 0.f};

#pragma unroll
        for (int kt = 0; kt < 4; ++kt) {
            const char* pA = gA + (size_t)kt * 16384;
            const char* pB = gB + (size_t)(nt * 4 + kt) * 16384;
            v8i av[4], bv[4];
#pragma unroll
            for (int mi = 0; mi < 4; mi++) {
                union { uint4 q[2]; v8i v; } uu;
                uu.q[0] = *(const uint4*)(pA + mi * 2048);
                uu.q[1] = *(const uint4*)(pA + mi * 2048 + 1024);
                av[mi] = uu.v;
            }
#pragma unroll
            for (int ni = 0; ni < 4; ni++) {
                union { uint4 q[2]; v8i v; } uu;
                uu.q[0] = *(const uint4*)(pB + ni * 2048);
                uu.q[1] = *(const uint4*)(pB + ni * 2048 + 1024);
                bv[ni] = uu.v;
            }
#pragma unroll
            for (int mi = 0; mi < 4; mi++)
#pragma unroll
                for (int ni = 0; ni < 4; ni++)
                    acc[mi][ni] = __builtin_amdgcn_mfma_scale_f32_16x16x128_f8f6f4(
                        av[mi], bv[ni], acc[mi][ni], 0, 0,
                        0, 0x7F7F7F7F, 0, 0x7F7F7F7F);  // scales = 1.0 (e8m0 127)
        }

        // fold: running fp32 min of (cnorm - 2*dot); teacher value captured separately
        const int n0 = (nq * 4 + nt) * 128;
        float cn[4]; int col[4];
#pragma unroll
        for (int ni = 0; ni < 4; ni++) {
            col[ni] = n0 + wc * 64 + ni * 16 + l15;
            cn[ni] = cnorm[col[ni]];
        }
#pragma unroll
        for (int mi = 0; mi < 4; mi++)
#pragma unroll
            for (int r = 0; r < 4; r++) {
                int t = tch[mi][r];
#pragma unroll
                for (int ni = 0; ni < 4; ni++) {
                    float val = fmaf(-2.0f, acc[mi][ni][r], cn[ni]);
                    bool ist = (col[ni] == t);
                    minv[mi][r] = fminf(minv[mi][r], ist ? INF : val);
                    posv[mi][r] = fminf(posv[mi][r], ist ? val : INF);
                }
            }
    }

    const int slot = nq * 2 + wc;  // 0..15
#pragma unroll
    for (int mi = 0; mi < 4; mi++)
#pragma unroll
        for (int r = 0; r < 4; r++) {
            float mn = minv[mi][r], ps = posv[mi][r];
#pragma unroll
            for (int off = 1; off < 16; off <<= 1) {
                mn = fminf(mn, __shfl_xor(mn, off));
                ps = fminf(ps, __shfl_xor(ps, off));
            }
            if (l15 == 0) {
                int m = m0 + wr * 64 + mi * 16 + quad * 4 + r;
                negq[(size_t)slot * NM + m] = mn;
                posq[(size_t)slot * NM + m] = ps;
            }
        }
}

// ---- kernel 3: per-row reduce over 16 slots + ticketed finalize (64 blocks only) ----
__global__ void reduce_final(const float* __restrict__ negq, const float* __restrict__ posq,
                             const float* __restrict__ npart, const int* __restrict__ lengths,
                             float* __restrict__ accum, unsigned int* __restrict__ ticket,
                             float* __restrict__ out) {
    const float INF = __builtin_inff();
    const int m = blockIdx.x * 256 + threadIdx.x;
    float mn = INF, ps = INF;
#pragma unroll
    for (int s = 0; s < 16; s++) {
        mn = fminf(mn, negq[(size_t)s * NM + m]);  // coalesced
        ps = fminf(ps, posq[(size_t)s * NM + m]);
    }
    float zn = npart[m] + npart[NM + m] + npart[2 * NM + m] + npart[3 * NM + m];
    float negd = sqrtf(fmaxf(zn + mn, 1e-12f));
    float posd = sqrtf(fmaxf(zn + ps, 1e-12f));
    float tri = fmaxf(posd - negd + MARGIN_F, 0.0f);
    int b = m >> 11;
    int tt = m & (NT - 1);
    int flen = lengths[b] / ENC_STRIDE;
    float val = (tt < flen) ? tri : 0.0f;  // select (not multiply): NaN/garbage-safe

    __shared__ float red[4];
#pragma unroll
    for (int off = 1; off < 64; off <<= 1) val += __shfl_xor(val, off);
    int lane = threadIdx.x & 63, w = threadIdx.x >> 6;
    if (lane == 0) red[w] = val;
    __syncthreads();
    if (threadIdx.x == 0) {
        atomicAdd(accum, red[0] + red[1] + red[2] + red[3]);
        __threadfence();
        unsigned int old = atomicAdd(ticket, 1u);
        if (old == 63u) {  // last block: all adds are visible
            float total = atomicAdd(accum, 0.0f);
            float cnt = 0.0f;
            for (int bb = 0; bb < NB; bb++) cnt += (float)(lengths[bb] / ENC_STRIDE);
            out[0] = total / (cnt + 1e-8f);
        }
    }
}

extern "C" void kernel_launch(void* const* d_in, const int* in_sizes, int n_in,
                              void* d_out, int out_size, void* d_ws, size_t ws_size,
                              hipStream_t stream) {
    const float* sf = (const float*)d_in[0];
    const int* teacher = (const int*)d_in[1];
    const float* cb = (const float*)d_in[2];
    const int* lengths = (const int*)d_in[3];

    char* ws = (char*)d_ws;
    unsigned char* Zq = (unsigned char*)(ws);                  //  8,388,608 B
    unsigned char* Cq = (unsigned char*)(ws + 8388608);        //  2,097,152 B
    float* cnorm = (float*)(ws + 10485760);                    //     16,384 B
    float* npart = (float*)(ws + 10502144);                    //    262,144 B (4 x NM)
    float* negq = (float*)(ws + 10764288);                     //  1,048,576 B (16 x NM)
    float* posq = (float*)(ws + 11812864);                     //  1,048,576 B
    float* accum = (float*)(ws + 12861440);                    //          4 B
    unsigned int* ticket = (unsigned int*)(ws + 12861444);     //          4 B

    prep_fused<<<1280, 256, 0, stream>>>(sf, cb, lengths, Zq, npart, Cq, cnorm, accum, ticket);
    triplet_main<<<1024, 256, 0, stream>>>(Zq, Cq, cnorm, teacher, lengths, negq, posq);
    reduce_final<<<64, 256, 0, stream>>>(negq, posq, npart, lengths, accum, ticket,
                                         (float*)d_out);
}

// Round 6
// 134.675 us; speedup vs baseline: 1.8099x; 1.8099x over previous
//
#include <hip/hip_runtime.h>
#include <hip/hip_bf16.h>

typedef float f32x4 __attribute__((ext_vector_type(4)));
typedef int v8i __attribute__((ext_vector_type(8)));

#define NB 8
#define ND 512
#define NT 2048
#define NCODES 4096
#define NM (NB * NT)
#define MARGIN_F 0.2f
#define ENC_STRIDE 320

// MX fragment image (Zq, Cq), fp8 e4m3:
//   tile (R_, K_) = 128 rows x 128 k = 16 KB at ((R_*4 + K_) * 16384)
//   fragment rg (0..7) = 16 rows x 128 k = 2048 B at rg*2048 within tile
//   bytes [0,1024): lane l's 16 B at l*16 = row rg*16+(l&15), k = (l>>4)*32 + 0..15
//   bytes [1024,2048): same lanes, k = (l>>4)*32 + 16..31

// Map a linear rank to the rank-th SURVIVING tile (tiles of 2^shift rows within each
// batch's valid prefix). Survivor compaction keeps live blocks contiguous in blockIdx.
static __device__ inline bool rank_decode(const int* __restrict__ lengths, int rank,
                                          int shift, int& b, int& tib) {
    int acc = 0;
    bool ok = false;
#pragma unroll
    for (int bb = 0; bb < NB; bb++) {
        int fl = lengths[bb] / ENC_STRIDE;
        int c = (fl + ((1 << shift) - 1)) >> shift;  // ceil(fl / tile_rows)
        if (!ok && rank < acc + c) { b = bb; tib = rank - acc; ok = true; }
        acc += c;
    }
    return ok;
}

// ---- kernel 1: fused prep. blocks [0,1024): student (compacted); [1024,1280): codebook ----
__global__ void prep_fused(const float* __restrict__ sf, const float* __restrict__ cb,
                           const int* __restrict__ lengths,
                           unsigned char* __restrict__ Zq, float* __restrict__ npart,
                           unsigned char* __restrict__ Cq, float* __restrict__ cnorm,
                           float* __restrict__ accum, unsigned int* __restrict__ ticket) {
    __shared__ float tile[128][65];
    __shared__ float redc[4][16];
    const int tid = threadIdx.x;  // 256
    const int wave = tid >> 6, lane = tid & 63, l15 = lane & 15, kq = lane >> 4;

    if (blockIdx.x < 1024) {
        const int bx = blockIdx.x;
        int b, tt;
        if (!rank_decode(lengths, bx >> 2, 6, b, tt)) return;  // 64-row student tiles
        const int t0 = tt * 64;
        const int d0 = (bx & 3) * 128;
        const float* src = sf + (size_t)b * ND * NT;
#pragma unroll
        for (int it = 0; it < 8; it++) {
            int idx = it * 256 + tid;
            int d = idx >> 4, t4 = (idx & 15) * 4;
            float4 v = *(const float4*)(src + (size_t)(d0 + d) * NT + t0 + t4);  // coalesced
            tile[d][t4] = v.x; tile[d][t4 + 1] = v.y; tile[d][t4 + 2] = v.z; tile[d][t4 + 3] = v.w;
        }
        __syncthreads();
        const int m0 = b * NT + t0;
        {
            const int trow = wave * 16 + l15;
            unsigned char q[32];
#pragma unroll
            for (int j = 0; j < 32; j += 2) {
                float a = tile[kq * 32 + j][trow];
                float c = tile[kq * 32 + j + 1][trow];
                int p = __builtin_amdgcn_cvt_pk_fp8_f32(a, c, 0, false);
                q[j] = (unsigned char)(p & 0xFF);
                q[j + 1] = (unsigned char)((p >> 8) & 0xFF);
            }
            const int M_ = m0 >> 7, rg = ((m0 >> 4) & 7) + wave, K_ = d0 >> 7;
            char* base = (char*)Zq + ((size_t)((M_ * 4 + K_) * 8 + rg)) * 2048;
            *(uint4*)(base + lane * 16) = *(uint4*)&q[0];
            *(uint4*)(base + 1024 + lane * 16) = *(uint4*)&q[16];
        }
        if (tid < 64) {
            float s = 0.0f;
#pragma unroll 16
            for (int d = 0; d < 128; d++) {
                float v = tile[d][tid];
                s += v * v;
            }
            npart[(size_t)(d0 >> 7) * NM + m0 + tid] = s;
        }
    } else {
        if (blockIdx.x == 1279 && tid == 0) { *accum = 0.0f; *ticket = 0u; }
        const int r0 = (blockIdx.x - 1024) * 16;
        const int row = r0 + l15;
        const int K_ = wave;  // each wave handles one 128-k quarter
        const float* src = cb + (size_t)row * ND + K_ * 128 + kq * 32;
        unsigned char q[32];
        float s = 0.0f;
#pragma unroll
        for (int j4 = 0; j4 < 8; j4++) {
            float4 v = *(const float4*)(src + j4 * 4);
            s += v.x * v.x + v.y * v.y + v.z * v.z + v.w * v.w;
            int p0 = __builtin_amdgcn_cvt_pk_fp8_f32(v.x, v.y, 0, false);
            int p1 = __builtin_amdgcn_cvt_pk_fp8_f32(v.z, v.w, 0, false);
            q[j4 * 4 + 0] = (unsigned char)(p0 & 0xFF);
            q[j4 * 4 + 1] = (unsigned char)((p0 >> 8) & 0xFF);
            q[j4 * 4 + 2] = (unsigned char)(p1 & 0xFF);
            q[j4 * 4 + 3] = (unsigned char)((p1 >> 8) & 0xFF);
        }
        const int N_ = r0 >> 7, rg = (r0 >> 4) & 7;
        char* base = (char*)Cq + ((size_t)((N_ * 4 + K_) * 8 + rg)) * 2048;
        *(uint4*)(base + lane * 16) = *(uint4*)&q[0];
        *(uint4*)(base + 1024 + lane * 16) = *(uint4*)&q[16];
        s += __shfl_xor(s, 16);
        s += __shfl_xor(s, 32);
        if (lane < 16) redc[wave][l15] = s;
        __syncthreads();
        if (tid < 16) cnorm[r0 + tid] = redc[0][tid] + redc[1][tid] + redc[2][tid] + redc[3][tid];
    }
}

// ---- kernel 2: MX-fp8 GEMM, register-direct (no LDS/barriers), SPILL-PROOFED ----
// Session rule (R2/R3/R5): any structure exposing >=2 tile-steps of load destinations
// to the scheduler spills (hipcc hoists all unrolled iterations' loads). Fix: kt loop
// is DYNAMIC (unroll 1) -> per-iteration live set = av+bv (64 VGPR) + acc (64 AGPR)
// + addrs ~= 150; compiler can pipeline at most one iteration ahead within the
// launch_bounds cap. No barriers anywhere: waves free-run on compiler-counted vmcnt.
__global__ __launch_bounds__(256, 2) void triplet_main(
    const unsigned char* __restrict__ Zq, const unsigned char* __restrict__ Cq,
    const float* __restrict__ cnorm, const int* __restrict__ teacher,
    const int* __restrict__ lengths,
    float* __restrict__ negq, float* __restrict__ posq) {
    int b, tM;
    if (!rank_decode(lengths, (int)blockIdx.x >> 3, 7, b, tM)) return;  // 128-row tiles
    const int nq = blockIdx.x & 7;
    const int M_ = b * 16 + tM;
    const int m0 = M_ * 128;

    const int tid = threadIdx.x;
    const int wave = tid >> 6, lane = tid & 63;
    const int wr = wave >> 1, wc = wave & 1;
    const int l15 = lane & 15, quad = lane >> 4;

    const float INF = __builtin_inff();
    float minv[4][4], posv[4][4];
    int tch[4][4];
#pragma unroll
    for (int mi = 0; mi < 4; mi++)
#pragma unroll
        for (int r = 0; r < 4; r++) {
            minv[mi][r] = INF;
            posv[mi][r] = INF;
            tch[mi][r] = teacher[m0 + wr * 64 + mi * 16 + quad * 4 + r];
        }

    // Per-wave fragment bases into the global fragment images.
    // A fragment mi of k-tile kt:  gA + kt*16384 + mi*2048 (+1024 for hi half)
    // B fragment ni of tile (nt,kt): gB + (nt*4+kt)*16384 + ni*2048 (+1024)
    const char* gA = (const char*)Zq + (size_t)(M_ * 4) * 16384 + (wr * 4) * 2048 + lane * 16;
    const char* gB = (const char*)Cq + (size_t)(nq * 16) * 16384 + (wc * 4) * 2048 + lane * 16;

#pragma unroll 1
    for (int nt = 0; nt < 4; ++nt) {
        f32x4 acc[4][4];
#pragma unroll
        for (int mi = 0; mi < 4; mi++)
#pragma unroll
            for (int ni = 0; ni < 4; ni++)
                acc[mi][ni] = (f32x4){0.f, 0.f, 0.f, 0.f};

#pragma unroll 1  // DYNAMIC: bounded load-dest live range (the R5 spill fix)
        for (int kt = 0; kt < 4; ++kt) {
            const char* pA = gA + (size_t)kt * 16384;
            const char* pB = gB + (size_t)(nt * 4 + kt) * 16384;
            v8i av[4], bv[4];
#pragma unroll
            for (int mi = 0; mi < 4; mi++) {
                union { uint4 q[2]; v8i v; } uu;
                uu.q[0] = *(const uint4*)(pA + mi * 2048);
                uu.q[1] = *(const uint4*)(pA + mi * 2048 + 1024);
                av[mi] = uu.v;
            }
#pragma unroll
            for (int ni = 0; ni < 4; ni++) {
                union { uint4 q[2]; v8i v; } uu;
                uu.q[0] = *(const uint4*)(pB + ni * 2048);
                uu.q[1] = *(const uint4*)(pB + ni * 2048 + 1024);
                bv[ni] = uu.v;
            }
#pragma unroll
            for (int mi = 0; mi < 4; mi++)
#pragma unroll
                for (int ni = 0; ni < 4; ni++)
                    acc[mi][ni] = __builtin_amdgcn_mfma_scale_f32_16x16x128_f8f6f4(
                        av[mi], bv[ni], acc[mi][ni], 0, 0,
                        0, 0x7F7F7F7F, 0, 0x7F7F7F7F);  // scales = 1.0 (e8m0 127)
        }

        // fold: running fp32 min of (cnorm - 2*dot); teacher value captured separately
        const int n0 = (nq * 4 + nt) * 128;
        float cn[4]; int col[4];
#pragma unroll
        for (int ni = 0; ni < 4; ni++) {
            col[ni] = n0 + wc * 64 + ni * 16 + l15;
            cn[ni] = cnorm[col[ni]];
        }
#pragma unroll
        for (int mi = 0; mi < 4; mi++)
#pragma unroll
            for (int r = 0; r < 4; r++) {
                int t = tch[mi][r];
#pragma unroll
                for (int ni = 0; ni < 4; ni++) {
                    float val = fmaf(-2.0f, acc[mi][ni][r], cn[ni]);
                    bool ist = (col[ni] == t);
                    minv[mi][r] = fminf(minv[mi][r], ist ? INF : val);
                    posv[mi][r] = fminf(posv[mi][r], ist ? val : INF);
                }
            }
    }

    const int slot = nq * 2 + wc;  // 0..15
#pragma unroll
    for (int mi = 0; mi < 4; mi++)
#pragma unroll
        for (int r = 0; r < 4; r++) {
            float mn = minv[mi][r], ps = posv[mi][r];
#pragma unroll
            for (int off = 1; off < 16; off <<= 1) {
                mn = fminf(mn, __shfl_xor(mn, off));
                ps = fminf(ps, __shfl_xor(ps, off));
            }
            if (l15 == 0) {
                int m = m0 + wr * 64 + mi * 16 + quad * 4 + r;
                negq[(size_t)slot * NM + m] = mn;
                posq[(size_t)slot * NM + m] = ps;
            }
        }
}

// ---- kernel 3: per-row reduce over 16 slots + ticketed finalize (64 blocks only) ----
__global__ void reduce_final(const float* __restrict__ negq, const float* __restrict__ posq,
                             const float* __restrict__ npart, const int* __restrict__ lengths,
                             float* __restrict__ accum, unsigned int* __restrict__ ticket,
                             float* __restrict__ out) {
    const float INF = __builtin_inff();
    const int m = blockIdx.x * 256 + threadIdx.x;
    float mn = INF, ps = INF;
#pragma unroll
    for (int s = 0; s < 16; s++) {
        mn = fminf(mn, negq[(size_t)s * NM + m]);  // coalesced
        ps = fminf(ps, posq[(size_t)s * NM + m]);
    }
    float zn = npart[m] + npart[NM + m] + npart[2 * NM + m] + npart[3 * NM + m];
    float negd = sqrtf(fmaxf(zn + mn, 1e-12f));
    float posd = sqrtf(fmaxf(zn + ps, 1e-12f));
    float tri = fmaxf(posd - negd + MARGIN_F, 0.0f);
    int b = m >> 11;
    int tt = m & (NT - 1);
    int flen = lengths[b] / ENC_STRIDE;
    float val = (tt < flen) ? tri : 0.0f;  // select (not multiply): NaN/garbage-safe

    __shared__ float red[4];
#pragma unroll
    for (int off = 1; off < 64; off <<= 1) val += __shfl_xor(val, off);
    int lane = threadIdx.x & 63, w = threadIdx.x >> 6;
    if (lane == 0) red[w] = val;
    __syncthreads();
    if (threadIdx.x == 0) {
        atomicAdd(accum, red[0] + red[1] + red[2] + red[3]);
        __threadfence();
        unsigned int old = atomicAdd(ticket, 1u);
        if (old == 63u) {  // last block: all adds are visible
            float total = atomicAdd(accum, 0.0f);
            float cnt = 0.0f;
            for (int bb = 0; bb < NB; bb++) cnt += (float)(lengths[bb] / ENC_STRIDE);
            out[0] = total / (cnt + 1e-8f);
        }
    }
}

extern "C" void kernel_launch(void* const* d_in, const int* in_sizes, int n_in,
                              void* d_out, int out_size, void* d_ws, size_t ws_size,
                              hipStream_t stream) {
    const float* sf = (const float*)d_in[0];
    const int* teacher = (const int*)d_in[1];
    const float* cb = (const float*)d_in[2];
    const int* lengths = (const int*)d_in[3];

    char* ws = (char*)d_ws;
    unsigned char* Zq = (unsigned char*)(ws);                  //  8,388,608 B
    unsigned char* Cq = (unsigned char*)(ws + 8388608);        //  2,097,152 B
    float* cnorm = (float*)(ws + 10485760);                    //     16,384 B
    float* npart = (float*)(ws + 10502144);                    //    262,144 B (4 x NM)
    float* negq = (float*)(ws + 10764288);                     //  1,048,576 B (16 x NM)
    float* posq = (float*)(ws + 11812864);                     //  1,048,576 B
    float* accum = (float*)(ws + 12861440);                    //          4 B
    unsigned int* ticket = (unsigned int*)(ws + 12861444);     //          4 B

    prep_fused<<<1280, 256, 0, stream>>>(sf, cb, lengths, Zq, npart, Cq, cnorm, accum, ticket);
    triplet_main<<<1024, 256, 0, stream>>>(Zq, Cq, cnorm, teacher, lengths, negq, posq);
    reduce_final<<<64, 256, 0, stream>>>(negq, posq, npart, lengths, accum, ticket,
                                         (float*)d_out);
}